// Round 1
// baseline (44.671 us; speedup 1.0000x reference)
//
#include <hip/hip_runtime.h>

// TransE 'rhs' scoring: pred[b,n] = MARGIN - || (s+r)[b] - e[n] ||_2
// B=32, N=200000, D=64, fp32 in/out.
//
// Strategy: memory-bound (77 MB traffic, ~12 us floor). Use
// ||q-e||^2 = ||q||^2 + ||e||^2 - 2 q.e  -> 1 FMA per (b,n,d).
// Block = 64 threads (1 wave). Each thread owns NT=4 consecutive n columns
// and all 32 b rows (acc[32][4] in registers). q (8 KB) + qnorm staged in LDS
// once per block; q reads in the main loop are wave-uniform broadcasts.

#define DD 64
#define C4 16          // DD/4 float4 chunks per row
#define NT 4           // n-columns per thread
#define NB 32          // B, hardcoded for full unroll
#define MARGIN 9.0f

__global__ __launch_bounds__(64, 2)
void transe_kernel(const float* __restrict__ s_emb,
                   const float* __restrict__ rel_emb,
                   const float* __restrict__ emb_e,
                   float* __restrict__ out,
                   int N) {
    __shared__ float4 q_lds[NB * C4];   // q[b][c] at index b*16+c
    __shared__ float  qnorm[NB];

    const int l = threadIdx.x;          // 0..63

    // ---- Stage q = s + r into LDS (contiguous, conflict-free), qnorm partials.
    const float4* s4 = (const float4*)s_emb;
    const float4* r4 = (const float4*)rel_emb;
    float pn[8];
#pragma unroll
    for (int k = 0; k < 8; ++k) {
        int idx = k * 64 + l;           // 512 float4 total = 32x64 floats
        float4 sv = s4[idx];
        float4 rv = r4[idx];
        float4 q;
        q.x = sv.x + rv.x; q.y = sv.y + rv.y;
        q.z = sv.z + rv.z; q.w = sv.w + rv.w;
        q_lds[idx] = q;
        pn[k] = q.x*q.x + q.y*q.y + q.z*q.z + q.w*q.w;
    }
    // idx/16 = b = 4k + (l>>4): reduce over the 16 lanes sharing l>>4.
#pragma unroll
    for (int k = 0; k < 8; ++k) {
        float v = pn[k];
        v += __shfl_xor(v, 1, 16);
        v += __shfl_xor(v, 2, 16);
        v += __shfl_xor(v, 4, 16);
        v += __shfl_xor(v, 8, 16);
        if ((l & 15) == 0) qnorm[4*k + (l >> 4)] = v;
    }
    __syncthreads();

    // ---- Main: each thread handles n0..n0+3 for all 32 b.
    const int tid = blockIdx.x * 64 + l;
    const long n0 = (long)tid * NT;
    if (n0 >= N) return;                // N % NT == 0: whole tile valid

    const float4* e4 = (const float4*)emb_e;

    float acc[NB][NT];
#pragma unroll
    for (int b = 0; b < NB; ++b)
#pragma unroll
        for (int j = 0; j < NT; ++j) acc[b][j] = 0.f;

    float en[NT] = {0.f, 0.f, 0.f, 0.f};

    for (int c = 0; c < C4; ++c) {
        float4 ev[NT];
#pragma unroll
        for (int j = 0; j < NT; ++j) {
            ev[j] = e4[(n0 + j) * C4 + c];
            en[j] = fmaf(ev[j].x, ev[j].x, en[j]);
            en[j] = fmaf(ev[j].y, ev[j].y, en[j]);
            en[j] = fmaf(ev[j].z, ev[j].z, en[j]);
            en[j] = fmaf(ev[j].w, ev[j].w, en[j]);
        }
#pragma unroll
        for (int b = 0; b < NB; ++b) {
            float4 qv = q_lds[b * C4 + c];   // wave-uniform broadcast read
#pragma unroll
            for (int j = 0; j < NT; ++j) {
                acc[b][j] = fmaf(qv.x, ev[j].x, acc[b][j]);
                acc[b][j] = fmaf(qv.y, ev[j].y, acc[b][j]);
                acc[b][j] = fmaf(qv.z, ev[j].z, acc[b][j]);
                acc[b][j] = fmaf(qv.w, ev[j].w, acc[b][j]);
            }
        }
    }

    // ---- Epilogue: d2 = qn + en - 2*dot; pred = MARGIN - sqrt(d2). float4 store.
    float4* out4 = (float4*)out;
    const long nq = N / 4;
#pragma unroll
    for (int b = 0; b < NB; ++b) {
        float qn = qnorm[b];
        float4 o;
        o.x = MARGIN - sqrtf(fmaxf(fmaf(-2.f, acc[b][0], qn + en[0]), 0.f));
        o.y = MARGIN - sqrtf(fmaxf(fmaf(-2.f, acc[b][1], qn + en[1]), 0.f));
        o.z = MARGIN - sqrtf(fmaxf(fmaf(-2.f, acc[b][2], qn + en[2]), 0.f));
        o.w = MARGIN - sqrtf(fmaxf(fmaf(-2.f, acc[b][3], qn + en[3]), 0.f));
        out4[(long)b * nq + tid] = o;
    }
}

extern "C" void kernel_launch(void* const* d_in, const int* in_sizes, int n_in,
                              void* d_out, int out_size, void* d_ws, size_t ws_size,
                              hipStream_t stream) {
    const float* s = (const float*)d_in[0];
    const float* r = (const float*)d_in[1];
    const float* e = (const float*)d_in[2];
    float* out = (float*)d_out;

    const int N = in_sizes[2] / DD;            // 200000
    const int threads_n = (N + NT - 1) / NT;   // 50000
    const int grid = (threads_n + 63) / 64;    // 782

    transe_kernel<<<grid, 64, 0, stream>>>(s, r, e, out, N);
}